// Round 1
// baseline (12431.294 us; speedup 1.0000x reference)
//
#include <hip/hip_runtime.h>
#include <stdint.h>

// JAX PRNG mode: 1 = jax_threefry_partitionable=True (default in jax >= 0.4.36/0.5),
// 0 = legacy original threefry counter layout. Flip if masks mismatch (absmax ~0.3).
#define PARTITIONABLE 1

#define NSAMP 16
#define BATCH 128
#define SEQLEN 32
#define SDIM 8
#define ODIM 4
#define HID 800
#define MROWS (NSAMP * BATCH) /* 2048 */
#define KEEPP 0.8f

// ---------------- threefry2x32 (Random123 / JAX, 20 rounds) ----------------
__host__ __device__ __forceinline__ void tf2x32(uint32_t k0, uint32_t k1,
                                                uint32_t x0, uint32_t x1,
                                                uint32_t& o0, uint32_t& o1) {
  uint32_t ks2 = k0 ^ k1 ^ 0x1BD11BDAu;
  x0 += k0; x1 += k1;
#define TFR(r) { x0 += x1; x1 = (x1 << (r)) | (x1 >> (32 - (r))); x1 ^= x0; }
  TFR(13) TFR(15) TFR(26) TFR(6)
  x0 += k1; x1 += ks2 + 1u;
  TFR(17) TFR(29) TFR(16) TFR(24)
  x0 += ks2; x1 += k0 + 2u;
  TFR(13) TFR(15) TFR(26) TFR(6)
  x0 += k0; x1 += k1 + 3u;
  TFR(17) TFR(29) TFR(16) TFR(24)
  x0 += k1; x1 += ks2 + 4u;
  TFR(13) TFR(15) TFR(26) TFR(6)
  x0 += ks2; x1 += k0 + 5u;
#undef TFR
  o0 = x0; o1 = x1;
}

__device__ __forceinline__ float bits_to_unit(uint32_t bits) {
  return __uint_as_float((bits >> 9) | 0x3F800000u) - 1.0f;
}

__device__ __forceinline__ float tf_uniform_part(uint32_t k0, uint32_t k1, uint32_t idx) {
  uint32_t b1, b2;
  tf2x32(k0, k1, 0u, idx, b1, b2);
  return bits_to_unit(b1 ^ b2);
}

// ---------------- a_ens = a * m1 / keep ----------------
__global__ void a_ens_kernel(const float* __restrict__ a, float* __restrict__ a_ens,
                             uint32_t k0, uint32_t k1) {
#if PARTITIONABLE
  int base = (blockIdx.x * blockDim.x + threadIdx.x) * 4;
  if (base >= MROWS * HID) return;
  int row = base / HID;
  int b = row % BATCH;
  int col = base - row * HID;
  float4 av = *reinterpret_cast<const float4*>(a + b * HID + col);
  float4 ov;
#pragma unroll
  for (int q = 0; q < 4; ++q) {
    float u = tf_uniform_part(k0, k1, (uint32_t)(base + q));
    (&ov.x)[q] = (&av.x)[q] * ((u < KEEPP) ? 1.25f : 0.0f);
  }
  *reinterpret_cast<float4*>(a_ens + base) = ov;
#else
  const int Hh = MROWS * HID / 2; // 819200
  int base = (blockIdx.x * blockDim.x + threadIdx.x) * 4;
  if (base >= Hh) return;
  int row = base / HID;
  int b = row % BATCH;
  int col = base - row * HID;
  float4 av = *reinterpret_cast<const float4*>(a + b * HID + col); // same a for i and i+Hh (Hh % (BATCH*HID) aligns rows)
  float4 o1v, o2v;
#pragma unroll
  for (int q = 0; q < 4; ++q) {
    uint32_t y0, y1;
    tf2x32(k0, k1, (uint32_t)(base + q), (uint32_t)(base + q + Hh), y0, y1);
    (&o1v.x)[q] = (&av.x)[q] * ((bits_to_unit(y0) < KEEPP) ? 1.25f : 0.0f);
    (&o2v.x)[q] = (&av.x)[q] * ((bits_to_unit(y1) < KEEPP) ? 1.25f : 0.0f);
  }
  *reinterpret_cast<float4*>(a_ens + base) = o1v;
  *reinterpret_cast<float4*>(a_ens + base + Hh) = o2v;
#endif
}

// ---------------- fused GRU: h_new = GRUCell(a_ens, h) ----------------
// 6 simultaneous GEMM accumulators: g0..2 = a_ens x W_ih[r,z,n], g3..5 = h x W_hh[r,z,n]
#define TM 64
#define TN 32
#define TKT 16

__global__ __launch_bounds__(256) void gru_gemm_kernel(
    const float* __restrict__ a_ens, const float* __restrict__ h,
    const float* __restrict__ W_ih, const float* __restrict__ W_hh,
    const float* __restrict__ b_ih, const float* __restrict__ b_hh,
    float* __restrict__ h_new) {
  __shared__ float As[2][TKT][TM + 4];
  __shared__ float Bs[6][TKT][TN + 4];

  const int m0 = blockIdx.x * TM;
  const int n0 = blockIdx.y * TN;
  const int tid = threadIdx.x;

  float acc[6][4][2];
#pragma unroll
  for (int g = 0; g < 6; ++g)
#pragma unroll
    for (int i = 0; i < 4; ++i) { acc[g][i][0] = 0.0f; acc[g][i][1] = 0.0f; }

  const int arow = tid >> 2;        // 0..63
  const int akq = (tid & 3) * 4;    // 0,4,8,12
  const int tmb = (tid >> 4) * 4;   // 0..60
  const int tnb = (tid & 15) * 2;   // 0..30

  for (int k0 = 0; k0 < HID; k0 += TKT) {
    float4 v1 = *reinterpret_cast<const float4*>(a_ens + (m0 + arow) * HID + k0 + akq);
    float4 v2 = *reinterpret_cast<const float4*>(h + (m0 + arow) * HID + k0 + akq);
#pragma unroll
    for (int q = 0; q < 4; ++q) {
      As[0][akq + q][arow] = (&v1.x)[q];
      As[1][akq + q][arow] = (&v2.x)[q];
    }
#pragma unroll
    for (int q3 = 0; q3 < 3; ++q3) {
      int fid = q3 * 256 + tid;   // 0..767 ; 6 tiles x 128 float4
      int g = fid >> 7;
      int rem = fid & 127;
      int nrow = rem >> 2;        // 0..31
      int kq = (rem & 3) * 4;
      const float* W = (g < 3) ? W_ih : W_hh;
      int wrow = n0 + nrow + (g % 3) * HID;
      float4 v = *reinterpret_cast<const float4*>(W + wrow * HID + k0 + kq);
#pragma unroll
      for (int q = 0; q < 4; ++q) Bs[g][kq + q][nrow] = (&v.x)[q];
    }
    __syncthreads();
#pragma unroll
    for (int kk = 0; kk < TKT; ++kk) {
      float a1v[4], a2v[4];
#pragma unroll
      for (int i = 0; i < 4; ++i) {
        a1v[i] = As[0][kk][tmb + i];
        a2v[i] = As[1][kk][tmb + i];
      }
      float bv[6][2];
#pragma unroll
      for (int g = 0; g < 6; ++g) { bv[g][0] = Bs[g][kk][tnb]; bv[g][1] = Bs[g][kk][tnb + 1]; }
#pragma unroll
      for (int g = 0; g < 6; ++g) {
#pragma unroll
        for (int rm = 0; rm < 4; ++rm) {
          float aval = (g < 3) ? a1v[rm] : a2v[rm];
          acc[g][rm][0] = fmaf(aval, bv[g][0], acc[g][rm][0]);
          acc[g][rm][1] = fmaf(aval, bv[g][1], acc[g][rm][1]);
        }
      }
    }
    __syncthreads();
  }

#pragma unroll
  for (int rm = 0; rm < 4; ++rm) {
    int m = m0 + tmb + rm;
    int n = n0 + tnb;
    float2 hv = *reinterpret_cast<const float2*>(h + m * HID + n);
    float2 res;
#pragma unroll
    for (int rn = 0; rn < 2; ++rn) {
      int nc = n + rn;
      float gir = acc[0][rm][rn] + b_ih[nc];
      float giz = acc[1][rm][rn] + b_ih[nc + HID];
      float gin = acc[2][rm][rn] + b_ih[nc + 2 * HID];
      float ghr = acc[3][rm][rn] + b_hh[nc];
      float ghz = acc[4][rm][rn] + b_hh[nc + HID];
      float ghn = acc[5][rm][rn] + b_hh[nc + 2 * HID];
      float r = 1.0f / (1.0f + expf(-(gir + ghr)));
      float z = 1.0f / (1.0f + expf(-(giz + ghz)));
      float nval = tanhf(gin + r * ghn);
      float hval = (rn == 0) ? hv.x : hv.y;
      (&res.x)[rn] = (1.0f - z) * nval + z * hval;
    }
    *reinterpret_cast<float2*>(h_new + m * HID + n) = res;
  }
}

// ---------------- K_vec = h_new @ W_out^T + b_out, dropout m2, ens ----------------
__global__ void kvec_ens_kernel(const float* __restrict__ h_new,
                                const float* __restrict__ WoutT,  // [HID][32]
                                const float* __restrict__ b_out,
                                const float* __restrict__ x_pred, // [B][8]
                                const float* __restrict__ innov,  // [B][4]
                                float* __restrict__ ens,          // [NS][B][8]
                                uint32_t k0, uint32_t k1) {
  const int jb = blockIdx.x;         // 0..2047 (j*BATCH+b)
  const int b = jb & (BATCH - 1);
  const int tid = threadIdx.x;       // 256
  const int o = tid & 31;
  const int kk = tid >> 5;           // 0..7

  const float* hrow = h_new + jb * HID;
  float partial = 0.0f;
  for (int k = kk * 100; k < kk * 100 + 100; ++k)
    partial = fmaf(hrow[k], WoutT[k * 32 + o], partial);

  __shared__ float red[8][32];
  __shared__ float Kv[32];
  red[kk][o] = partial;
  __syncthreads();
  if (tid < 32) {
    float s = 0.0f;
#pragma unroll
    for (int q = 0; q < 8; ++q) s += red[q][tid];
    s += b_out[tid];
    uint32_t idx = (uint32_t)(jb * 32 + tid);
#if PARTITIONABLE
    float u = tf_uniform_part(k0, k1, idx);
#else
    const uint32_t H2 = (uint32_t)(MROWS * 32 / 2); // 32768
    uint32_t y0, y1, bits;
    if (idx < H2) { tf2x32(k0, k1, idx, idx + H2, y0, y1); bits = y0; }
    else          { tf2x32(k0, k1, idx - H2, idx, y0, y1); bits = y1; }
    float u = bits_to_unit(bits);
#endif
    Kv[tid] = (u < KEEPP) ? s * 1.25f : 0.0f;
  }
  __syncthreads();
  if (tid < SDIM) {
    float s = x_pred[b * SDIM + tid];
#pragma unroll
    for (int oo = 0; oo < ODIM; ++oo)
      s = fmaf(Kv[tid * ODIM + oo], innov[b * ODIM + oo], s);
    ens[jb * SDIM + tid] = s;
  }
}

// ---------------- ensemble stats + outputs + prep of next step ----------------
__global__ void reduce_prep_kernel(const float* __restrict__ ens,
                                   float* __restrict__ x_pred,
                                   float* __restrict__ innov,
                                   const float* __restrict__ y_seq, // [B][SEQ][4]
                                   const float* __restrict__ W1,    // [HID][12]
                                   const float* __restrict__ b1,
                                   float* __restrict__ a,           // [B][HID]
                                   float* __restrict__ out_xs, float* __restrict__ out_Ps,
                                   int t) {
  const int b = blockIdx.x;
  const int tid = threadIdx.x;
  __shared__ float e[NSAMP][SDIM];
  __shared__ float xf[SDIM];
  __shared__ float dxs[SDIM];
  __shared__ float xpn[SDIM];
  __shared__ float inv[ODIM];
  __shared__ float nin[SDIM + ODIM];

  if (t >= 0) {
    if (tid < NSAMP * SDIM) {
      int j = tid >> 3, s = tid & 7;
      e[j][s] = ens[(j * BATCH + b) * SDIM + s];
    }
    __syncthreads();
    if (tid < SDIM) {
      float s = 0.0f;
#pragma unroll
      for (int j = 0; j < NSAMP; ++j) s += e[j][tid];
      s *= (1.0f / NSAMP);
      xf[tid] = s;
      out_xs[(b * SEQLEN + t) * SDIM + tid] = s;
      dxs[tid] = s - x_pred[b * SDIM + tid];
    }
    __syncthreads();
    if (tid < SDIM * SDIM) {
      int s = tid >> 3, u = tid & 7;
      float accv = 0.0f;
#pragma unroll
      for (int j = 0; j < NSAMP; ++j)
        accv += (e[j][s] - xf[s]) * (e[j][u] - xf[u]);
      out_Ps[((b * SEQLEN + t) * SDIM + s) * SDIM + u] = accv * (1.0f / NSAMP);
    }
  } else {
    if (tid < SDIM) { xf[tid] = 0.0f; dxs[tid] = 0.0f; }
  }
  if (t == SEQLEN - 1) return;
  __syncthreads();
  if (tid < SDIM) {
    float x = xf[tid];
    float xp = 0.9f * x + 0.1f * sinf(x);
    xpn[tid] = xp;
    x_pred[b * SDIM + tid] = xp;
  }
  __syncthreads();
  if (tid < ODIM) {
    float yh = tanhf(xpn[tid]);
    float iv = y_seq[(b * SEQLEN + (t + 1)) * ODIM + tid] - yh;
    inv[tid] = iv;
    innov[b * ODIM + tid] = iv;
  }
  __syncthreads();
  if (tid == 0) {
    float nd = 0.0f;
    for (int s = 0; s < SDIM; ++s) nd += dxs[s] * dxs[s];
    nd = fmaxf(sqrtf(nd), 1e-12f);
    for (int s = 0; s < SDIM; ++s) nin[s] = dxs[s] / nd;
    float ni = 0.0f;
    for (int o2 = 0; o2 < ODIM; ++o2) ni += inv[o2] * inv[o2];
    ni = fmaxf(sqrtf(ni), 1e-12f);
    for (int o2 = 0; o2 < ODIM; ++o2) nin[SDIM + o2] = inv[o2] / ni;
  }
  __syncthreads();
  for (int i = tid; i < HID; i += blockDim.x) {
    float s = b1[i];
#pragma unroll
    for (int c = 0; c < 12; ++c) s = fmaf(nin[c], W1[i * 12 + c], s);
    a[b * HID + i] = fmaxf(s, 0.0f);
  }
}

__global__ void transpose_wout_kernel(const float* __restrict__ W_out, float* __restrict__ WoutT) {
  int i = blockIdx.x * 256 + threadIdx.x;
  if (i < 32 * HID) {
    int o = i / HID, k = i - o * HID;
    WoutT[k * 32 + o] = W_out[i];
  }
}

extern "C" void kernel_launch(void* const* d_in, const int* in_sizes, int n_in,
                              void* d_out, int out_size, void* d_ws, size_t ws_size,
                              hipStream_t stream) {
  (void)in_sizes; (void)n_in; (void)out_size; (void)ws_size;
  const float* y_seq = (const float*)d_in[0];
  const float* W1 = (const float*)d_in[1];
  const float* b1 = (const float*)d_in[2];
  const float* W_ih = (const float*)d_in[3];
  const float* W_hh = (const float*)d_in[4];
  const float* b_ih = (const float*)d_in[5];
  const float* b_hh = (const float*)d_in[6];
  const float* W_out = (const float*)d_in[7];
  const float* b_out = (const float*)d_in[8];

  float* ws = (float*)d_ws;
  size_t off = 0;
  float* h_a = ws + off;   off += (size_t)MROWS * HID;
  float* h_b = ws + off;   off += (size_t)MROWS * HID;
  float* a_ens = ws + off; off += (size_t)MROWS * HID;
  float* a_buf = ws + off; off += (size_t)BATCH * HID;
  float* WoutT = ws + off; off += (size_t)HID * 32;
  float* x_pred = ws + off; off += (size_t)BATCH * SDIM;
  float* innov = ws + off;  off += (size_t)BATCH * ODIM;
  float* ens = ws + off;    off += (size_t)NSAMP * BATCH * SDIM;

  float* out_xs = (float*)d_out;
  float* out_Ps = out_xs + (size_t)BATCH * SEQLEN * SDIM;

  hipMemsetAsync(h_a, 0, (size_t)MROWS * HID * sizeof(float), stream);
  transpose_wout_kernel<<<100, 256, 0, stream>>>(W_out, WoutT);
  reduce_prep_kernel<<<BATCH, 256, 0, stream>>>(ens, x_pred, innov, y_seq, W1, b1,
                                                a_buf, out_xs, out_Ps, -1);

  float* hc = h_a;
  float* hn = h_b;
  for (int t = 0; t < SEQLEN; ++t) {
    uint32_t kt0, kt1;
    tf2x32(0u, 42u, 0u, (uint32_t)t, kt0, kt1);   // fold_in(key(42), t)
    uint32_t k1a, k1b, k2a, k2b;
#if PARTITIONABLE
    tf2x32(kt0, kt1, 0u, 0u, k1a, k1b);  // split foldlike: block (0,0)
    tf2x32(kt0, kt1, 0u, 1u, k2a, k2b);  // block (0,1)
#else
    uint32_t p0a, p0b, p1a, p1b;
    tf2x32(kt0, kt1, 0u, 2u, p0a, p0b);  // pairs (0,2),(1,3)
    tf2x32(kt0, kt1, 1u, 3u, p1a, p1b);
    k1a = p0a; k1b = p1a; k2a = p0b; k2b = p1b;
#endif
#if PARTITIONABLE
    a_ens_kernel<<<1600, 256, 0, stream>>>(a_buf, a_ens, k1a, k1b);
#else
    a_ens_kernel<<<800, 256, 0, stream>>>(a_buf, a_ens, k1a, k1b);
#endif
    dim3 gg(MROWS / TM, HID / TN);
    gru_gemm_kernel<<<gg, 256, 0, stream>>>(a_ens, hc, W_ih, W_hh, b_ih, b_hh, hn);
    kvec_ens_kernel<<<MROWS, 256, 0, stream>>>(hn, WoutT, b_out, x_pred, innov, ens, k2a, k2b);
    reduce_prep_kernel<<<BATCH, 256, 0, stream>>>(ens, x_pred, innov, y_seq, W1, b1,
                                                  a_buf, out_xs, out_Ps, t);
    float* tmp = hc; hc = hn; hn = tmp;
  }
}

// Round 2
// 2264.160 us; speedup vs baseline: 5.4905x; 5.4905x over previous
//
#include <hip/hip_runtime.h>
#include <stdint.h>

#define NSAMP 16
#define BATCH 128
#define SEQLEN 32
#define SDIM 8
#define ODIM 4
#define HID 800
#define MROWS (NSAMP * BATCH) /* 2048 */
#define KEEPP 0.8f

typedef __attribute__((ext_vector_type(8))) short short8v;
typedef __attribute__((ext_vector_type(4))) float float4v;

// ---------------- threefry2x32 (JAX partitionable mode, verified R1) ----------------
__host__ __device__ __forceinline__ void tf2x32(uint32_t k0, uint32_t k1,
                                                uint32_t x0, uint32_t x1,
                                                uint32_t& o0, uint32_t& o1) {
  uint32_t ks2 = k0 ^ k1 ^ 0x1BD11BDAu;
  x0 += k0; x1 += k1;
#define TFR(r) { x0 += x1; x1 = (x1 << (r)) | (x1 >> (32 - (r))); x1 ^= x0; }
  TFR(13) TFR(15) TFR(26) TFR(6)
  x0 += k1; x1 += ks2 + 1u;
  TFR(17) TFR(29) TFR(16) TFR(24)
  x0 += ks2; x1 += k0 + 2u;
  TFR(13) TFR(15) TFR(26) TFR(6)
  x0 += k0; x1 += k1 + 3u;
  TFR(17) TFR(29) TFR(16) TFR(24)
  x0 += k1; x1 += ks2 + 4u;
  TFR(13) TFR(15) TFR(26) TFR(6)
  x0 += ks2; x1 += k0 + 5u;
#undef TFR
  o0 = x0; o1 = x1;
}

__device__ __forceinline__ float bits_to_unit(uint32_t bits) {
  return __uint_as_float((bits >> 9) | 0x3F800000u) - 1.0f;
}

__device__ __forceinline__ float tf_uniform_part(uint32_t k0, uint32_t k1, uint32_t idx) {
  uint32_t b1, b2;
  tf2x32(k0, k1, 0u, idx, b1, b2);
  return bits_to_unit(b1 ^ b2);
}

__device__ __forceinline__ ushort f2bf(float f) {
  uint32_t u = __float_as_uint(f);
  uint32_t r = (u + 0x7FFFu + ((u >> 16) & 1u)) >> 16;
  return (ushort)r;
}

// ---------------- weight conversion fp32 -> bf16 (once) ----------------
__global__ void convert_w_kernel(const float* __restrict__ W_ih, const float* __restrict__ W_hh,
                                 ushort* __restrict__ Wib, ushort* __restrict__ Whb) {
  int i = (blockIdx.x * 256 + threadIdx.x) * 4;
  if (i >= 2400 * HID) return;
  float4 v1 = *reinterpret_cast<const float4*>(W_ih + i);
  float4 v2 = *reinterpret_cast<const float4*>(W_hh + i);
  ushort4 o1, o2;
  o1.x = f2bf(v1.x); o1.y = f2bf(v1.y); o1.z = f2bf(v1.z); o1.w = f2bf(v1.w);
  o2.x = f2bf(v2.x); o2.y = f2bf(v2.y); o2.z = f2bf(v2.z); o2.w = f2bf(v2.w);
  *reinterpret_cast<ushort4*>(Wib + i) = o1;
  *reinterpret_cast<ushort4*>(Whb + i) = o2;
}

// ---------------- a_ens = bf16( a * m1 / keep ) ----------------
__global__ void a_ens_kernel(const float* __restrict__ a, ushort* __restrict__ aeb,
                             uint32_t k0, uint32_t k1) {
  int base = (blockIdx.x * blockDim.x + threadIdx.x) * 4;
  if (base >= MROWS * HID) return;
  int row = base / HID;
  int b = row % BATCH;
  int col = base - row * HID;
  float4 av = *reinterpret_cast<const float4*>(a + b * HID + col);
  ushort4 ov;
#pragma unroll
  for (int q = 0; q < 4; ++q) {
    float u = tf_uniform_part(k0, k1, (uint32_t)(base + q));
    float f = (&av.x)[q] * ((u < KEEPP) ? 1.25f : 0.0f);
    (&ov.x)[q] = f2bf(f);
  }
  *reinterpret_cast<ushort4*>(aeb + base) = ov;
}

// ---------------- MFMA GRU: h_new = GRUCell(a_ens, h) ----------------
// TM=128 (4 waves x 32 rows), TN=32. 6 gate-GEMMs (a_ens x W_ih[r,z,n], h x W_hh[r,z,n])
// LDS: A[2][128][32]bf16 (16KB) + B[6][32][32]bf16 (12KB) = 28KB, staged via
// global_load_lds(16B) with pre-swizzled source; reads XOR-swizzled (slot ^= (row>>1)&3).
__global__ __launch_bounds__(256, 2) void gru_mfma_kernel(
    const ushort* __restrict__ aeb, const ushort* __restrict__ hb,
    const ushort* __restrict__ Wib, const ushort* __restrict__ Whb,
    const float* __restrict__ h_old,
    const float* __restrict__ b_ih, const float* __restrict__ b_hh,
    float* __restrict__ h_new, ushort* __restrict__ h_new_b) {
  __shared__ __align__(1024) char lds[28672];

  const int tid = threadIdx.x;
  const int wid = tid >> 6;
  const int lane = tid & 63;
  const int m0 = blockIdx.x * 128;
  const int n0 = blockIdx.y * 32;

  float4v acc[6][2][2];
#pragma unroll
  for (int g = 0; g < 6; ++g)
#pragma unroll
    for (int mf = 0; mf < 2; ++mf)
#pragma unroll
      for (int nf = 0; nf < 2; ++nf)
        acc[g][mf][nf] = (float4v)(0.0f);

  const int rlo = lane >> 2;                        // 0..15 row within 16-row chunk
  const int sslot = (lane & 3) ^ ((lane >> 3) & 3); // pre-swizzled source 16B slot
  const int kg = lane >> 4;                         // mfma k-group
  const int l15 = lane & 15;

  for (int k0 = 0; k0 < HID; k0 += 32) {
    // ---- stage: 28 x global_load_lds(16B), wave w takes instr w,w+4,...
    for (int i = wid; i < 28; i += 4) {
      const ushort* gsrc;
      int ldsoff;
      if (i < 16) {
        int src = i >> 3;       // 0=a_ens, 1=h(bf16)
        int i8 = i & 7;         // 16-row chunk
        ldsoff = src * 8192 + i8 * 1024;
        const ushort* base = (src == 0) ? aeb : hb;
        gsrc = base + (size_t)(m0 + i8 * 16 + rlo) * HID + k0 + sslot * 8;
      } else {
        int j = i - 16;
        int g = j >> 1;
        int half = j & 1;
        ldsoff = 16384 + g * 2048 + half * 1024;
        int wrow = (g < 3) ? (n0 + g * HID + half * 16 + rlo)
                           : (n0 + (g - 3) * HID + half * 16 + rlo);
        const ushort* base = (g < 3) ? Wib : Whb;
        gsrc = base + (size_t)wrow * HID + k0 + sslot * 8;
      }
      __builtin_amdgcn_global_load_lds(
          (const __attribute__((address_space(1))) void*)gsrc,
          (__attribute__((address_space(3))) void*)&lds[ldsoff], 16, 0, 0);
    }
    __syncthreads();

    // ---- fragments
    short8v bfr[6][2];
#pragma unroll
    for (int g = 0; g < 6; ++g)
#pragma unroll
      for (int nf = 0; nf < 2; ++nf) {
        int row = nf * 16 + l15;
        int off = 16384 + g * 2048 + row * 64 + ((kg ^ ((row >> 1) & 3)) << 4);
        bfr[g][nf] = *reinterpret_cast<const short8v*>(&lds[off]);
      }
    short8v afr[2][2];
#pragma unroll
    for (int src = 0; src < 2; ++src)
#pragma unroll
      for (int mf = 0; mf < 2; ++mf) {
        int row = wid * 32 + mf * 16 + l15;
        int off = src * 8192 + row * 64 + ((kg ^ ((row >> 1) & 3)) << 4);
        afr[src][mf] = *reinterpret_cast<const short8v*>(&lds[off]);
      }
#pragma unroll
    for (int g = 0; g < 6; ++g) {
      const int src = (g < 3) ? 0 : 1;
#pragma unroll
      for (int mf = 0; mf < 2; ++mf)
#pragma unroll
        for (int nf = 0; nf < 2; ++nf)
          acc[g][mf][nf] = __builtin_amdgcn_mfma_f32_16x16x32_bf16(
              afr[src][mf], bfr[g][nf], acc[g][mf][nf], 0, 0, 0);
    }
    __syncthreads();
  }

  // ---- epilogue: gates + state update; C/D: col=lane&15, row=(lane>>4)*4+reg
  const int rowq = (lane >> 4) * 4;
#pragma unroll
  for (int nf = 0; nf < 2; ++nf) {
    const int col = n0 + nf * 16 + l15;
    const float bir = b_ih[col], biz = b_ih[col + HID], bin = b_ih[col + 2 * HID];
    const float bhr = b_hh[col], bhz = b_hh[col + HID], bhn = b_hh[col + 2 * HID];
#pragma unroll
    for (int mf = 0; mf < 2; ++mf) {
#pragma unroll
      for (int reg = 0; reg < 4; ++reg) {
        const int m = m0 + wid * 32 + mf * 16 + rowq + reg;
        float gir = acc[0][mf][nf][reg] + bir;
        float giz = acc[1][mf][nf][reg] + biz;
        float gin = acc[2][mf][nf][reg] + bin;
        float ghr = acc[3][mf][nf][reg] + bhr;
        float ghz = acc[4][mf][nf][reg] + bhz;
        float ghn = acc[5][mf][nf][reg] + bhn;
        float r = 1.0f / (1.0f + expf(-(gir + ghr)));
        float z = 1.0f / (1.0f + expf(-(giz + ghz)));
        float nval = tanhf(gin + r * ghn);
        float hv = h_old[(size_t)m * HID + col];
        float res = (1.0f - z) * nval + z * hv;
        h_new[(size_t)m * HID + col] = res;
        h_new_b[(size_t)m * HID + col] = f2bf(res);
      }
    }
  }
}

// ---------------- K_vec = h_new @ W_out^T + b_out, dropout m2, ens ----------------
__global__ void kvec_ens_kernel(const float* __restrict__ h_new,
                                const float* __restrict__ WoutT,  // [HID][32]
                                const float* __restrict__ b_out,
                                const float* __restrict__ x_pred, // [B][8]
                                const float* __restrict__ innov,  // [B][4]
                                float* __restrict__ ens,          // [NS][B][8]
                                uint32_t k0, uint32_t k1) {
  const int jb = blockIdx.x;
  const int b = jb & (BATCH - 1);
  const int tid = threadIdx.x;
  const int o = tid & 31;
  const int kk = tid >> 5;

  const float* hrow = h_new + (size_t)jb * HID;
  float partial = 0.0f;
  for (int k = kk * 100; k < kk * 100 + 100; ++k)
    partial = fmaf(hrow[k], WoutT[k * 32 + o], partial);

  __shared__ float red[8][32];
  __shared__ float Kv[32];
  red[kk][o] = partial;
  __syncthreads();
  if (tid < 32) {
    float s = 0.0f;
#pragma unroll
    for (int q = 0; q < 8; ++q) s += red[q][tid];
    s += b_out[tid];
    float u = tf_uniform_part(k0, k1, (uint32_t)(jb * 32 + tid));
    Kv[tid] = (u < KEEPP) ? s * 1.25f : 0.0f;
  }
  __syncthreads();
  if (tid < SDIM) {
    float s = x_pred[b * SDIM + tid];
#pragma unroll
    for (int oo = 0; oo < ODIM; ++oo)
      s = fmaf(Kv[tid * ODIM + oo], innov[b * ODIM + oo], s);
    ens[jb * SDIM + tid] = s;
  }
}

// ---------------- ensemble stats + outputs + prep of next step ----------------
__global__ void reduce_prep_kernel(const float* __restrict__ ens,
                                   float* __restrict__ x_pred,
                                   float* __restrict__ innov,
                                   const float* __restrict__ y_seq,
                                   const float* __restrict__ W1,
                                   const float* __restrict__ b1,
                                   float* __restrict__ a,
                                   float* __restrict__ out_xs, float* __restrict__ out_Ps,
                                   int t) {
  const int b = blockIdx.x;
  const int tid = threadIdx.x;
  __shared__ float e[NSAMP][SDIM];
  __shared__ float xf[SDIM];
  __shared__ float dxs[SDIM];
  __shared__ float xpn[SDIM];
  __shared__ float inv[ODIM];
  __shared__ float nin[SDIM + ODIM];

  if (t >= 0) {
    if (tid < NSAMP * SDIM) {
      int j = tid >> 3, s = tid & 7;
      e[j][s] = ens[(j * BATCH + b) * SDIM + s];
    }
    __syncthreads();
    if (tid < SDIM) {
      float s = 0.0f;
#pragma unroll
      for (int j = 0; j < NSAMP; ++j) s += e[j][tid];
      s *= (1.0f / NSAMP);
      xf[tid] = s;
      out_xs[(b * SEQLEN + t) * SDIM + tid] = s;
      dxs[tid] = s - x_pred[b * SDIM + tid];
    }
    __syncthreads();
    if (tid < SDIM * SDIM) {
      int s = tid >> 3, u = tid & 7;
      float accv = 0.0f;
#pragma unroll
      for (int j = 0; j < NSAMP; ++j)
        accv += (e[j][s] - xf[s]) * (e[j][u] - xf[u]);
      out_Ps[((b * SEQLEN + t) * SDIM + s) * SDIM + u] = accv * (1.0f / NSAMP);
    }
  } else {
    if (tid < SDIM) { xf[tid] = 0.0f; dxs[tid] = 0.0f; }
  }
  if (t == SEQLEN - 1) return;
  __syncthreads();
  if (tid < SDIM) {
    float x = xf[tid];
    float xp = 0.9f * x + 0.1f * sinf(x);
    xpn[tid] = xp;
    x_pred[b * SDIM + tid] = xp;
  }
  __syncthreads();
  if (tid < ODIM) {
    float yh = tanhf(xpn[tid]);
    float iv = y_seq[(b * SEQLEN + (t + 1)) * ODIM + tid] - yh;
    inv[tid] = iv;
    innov[b * ODIM + tid] = iv;
  }
  __syncthreads();
  if (tid == 0) {
    float nd = 0.0f;
    for (int s = 0; s < SDIM; ++s) nd += dxs[s] * dxs[s];
    nd = fmaxf(sqrtf(nd), 1e-12f);
    for (int s = 0; s < SDIM; ++s) nin[s] = dxs[s] / nd;
    float ni = 0.0f;
    for (int o2 = 0; o2 < ODIM; ++o2) ni += inv[o2] * inv[o2];
    ni = fmaxf(sqrtf(ni), 1e-12f);
    for (int o2 = 0; o2 < ODIM; ++o2) nin[SDIM + o2] = inv[o2] / ni;
  }
  __syncthreads();
  for (int i = tid; i < HID; i += blockDim.x) {
    float s = b1[i];
#pragma unroll
    for (int c = 0; c < 12; ++c) s = fmaf(nin[c], W1[i * 12 + c], s);
    a[b * HID + i] = fmaxf(s, 0.0f);
  }
}

__global__ void transpose_wout_kernel(const float* __restrict__ W_out, float* __restrict__ WoutT) {
  int i = blockIdx.x * 256 + threadIdx.x;
  if (i < 32 * HID) {
    int o = i / HID, k = i - o * HID;
    WoutT[k * 32 + o] = W_out[i];
  }
}

extern "C" void kernel_launch(void* const* d_in, const int* in_sizes, int n_in,
                              void* d_out, int out_size, void* d_ws, size_t ws_size,
                              hipStream_t stream) {
  (void)in_sizes; (void)n_in; (void)out_size; (void)ws_size;
  const float* y_seq = (const float*)d_in[0];
  const float* W1 = (const float*)d_in[1];
  const float* b1 = (const float*)d_in[2];
  const float* W_ih = (const float*)d_in[3];
  const float* W_hh = (const float*)d_in[4];
  const float* b_ih = (const float*)d_in[5];
  const float* b_hh = (const float*)d_in[6];
  const float* W_out = (const float*)d_in[7];
  const float* b_out = (const float*)d_in[8];

  char* ws = (char*)d_ws;
  size_t off = 0;
  float* h_a = (float*)(ws + off);   off += (size_t)MROWS * HID * 4;
  float* h_b = (float*)(ws + off);   off += (size_t)MROWS * HID * 4;
  ushort* hb_a = (ushort*)(ws + off); off += (size_t)MROWS * HID * 2;
  ushort* hb_b = (ushort*)(ws + off); off += (size_t)MROWS * HID * 2;
  ushort* aeb = (ushort*)(ws + off);  off += (size_t)MROWS * HID * 2;
  ushort* Wib = (ushort*)(ws + off);  off += (size_t)2400 * HID * 2;
  ushort* Whb = (ushort*)(ws + off);  off += (size_t)2400 * HID * 2;
  float* a_buf = (float*)(ws + off);  off += (size_t)BATCH * HID * 4;
  float* WoutT = (float*)(ws + off);  off += (size_t)HID * 32 * 4;
  float* x_pred = (float*)(ws + off); off += (size_t)BATCH * SDIM * 4;
  float* innov = (float*)(ws + off);  off += (size_t)BATCH * ODIM * 4;
  float* ens = (float*)(ws + off);    off += (size_t)NSAMP * BATCH * SDIM * 4;

  float* out_xs = (float*)d_out;
  float* out_Ps = out_xs + (size_t)BATCH * SEQLEN * SDIM;

  hipMemsetAsync(h_a, 0, (size_t)MROWS * HID * 4, stream);
  hipMemsetAsync(hb_a, 0, (size_t)MROWS * HID * 2, stream);
  convert_w_kernel<<<1875, 256, 0, stream>>>(W_ih, W_hh, Wib, Whb);
  transpose_wout_kernel<<<100, 256, 0, stream>>>(W_out, WoutT);
  reduce_prep_kernel<<<BATCH, 256, 0, stream>>>(ens, x_pred, innov, y_seq, W1, b1,
                                                a_buf, out_xs, out_Ps, -1);

  float* hc = h_a;  float* hn = h_b;
  ushort* hcb = hb_a; ushort* hnb = hb_b;
  for (int t = 0; t < SEQLEN; ++t) {
    uint32_t kt0, kt1;
    tf2x32(0u, 42u, 0u, (uint32_t)t, kt0, kt1);   // fold_in(key(42), t)
    uint32_t k1a, k1b, k2a, k2b;
    tf2x32(kt0, kt1, 0u, 0u, k1a, k1b);  // split -> block (0,0)
    tf2x32(kt0, kt1, 0u, 1u, k2a, k2b);  // split -> block (0,1)

    a_ens_kernel<<<1600, 256, 0, stream>>>(a_buf, aeb, k1a, k1b);
    dim3 gg(MROWS / 128, HID / 32);
    gru_mfma_kernel<<<gg, 256, 0, stream>>>(aeb, hcb, Wib, Whb, hc, b_ih, b_hh, hn, hnb);
    kvec_ens_kernel<<<MROWS, 256, 0, stream>>>(hn, WoutT, b_out, x_pred, innov, ens, k2a, k2b);
    reduce_prep_kernel<<<BATCH, 256, 0, stream>>>(ens, x_pred, innov, y_seq, W1, b1,
                                                  a_buf, out_xs, out_Ps, t);
    float* tmp = hc; hc = hn; hn = tmp;
    ushort* tmpb = hcb; hcb = hnb; hnb = tmpb;
  }
}